// Round 10
// baseline (488.466 us; speedup 1.0000x reference)
//
#include <hip/hip_runtime.h>
#include <hip/hip_bf16.h>
#include <stdint.h>

typedef unsigned short ushort_t;
typedef __attribute__((ext_vector_type(8))) short short8;
typedef __attribute__((ext_vector_type(4))) float floatx4;

__device__ __forceinline__ ushort_t f2b(float f) {
    unsigned u = __float_as_uint(f);
    unsigned r = (u + 0x7FFFu + ((u >> 16) & 1u)) >> 16;
    return (ushort_t)r;
}
__device__ __forceinline__ float b2f(ushort_t h) {
    return __uint_as_float(((unsigned)h) << 16);
}
__device__ __forceinline__ float elu1(float f) {
    return (f > 0.f) ? (f + 1.f) : __expf(f);
}

#define GLDS16(srcp, dstp)                                                          \
    __builtin_amdgcn_global_load_lds(                                               \
        (const __attribute__((address_space(1))) unsigned int*)(srcp),              \
        (__attribute__((address_space(3))) unsigned int*)(dstp), 16, 0, 0)

// ---------------- conversion kernels ----------------

__global__ void conv_bf16(const float* __restrict__ in, ushort_t* __restrict__ out, int n8) {
    for (int i = blockIdx.x * blockDim.x + threadIdx.x; i < n8; i += gridDim.x * blockDim.x) {
        const float4 f0 = *(const float4*)&in[(size_t)i * 8];
        const float4 f1 = *(const float4*)&in[(size_t)i * 8 + 4];
        ushort4 o0, o1;
        o0.x = f2b(f0.x); o0.y = f2b(f0.y); o0.z = f2b(f0.z); o0.w = f2b(f0.w);
        o1.x = f2b(f1.x); o1.y = f2b(f1.y); o1.z = f2b(f1.z); o1.w = f2b(f1.w);
        *(ushort4*)&out[(size_t)i * 8]     = o0;
        *(ushort4*)&out[(size_t)i * 8 + 4] = o1;
    }
}

__global__ void transpose_conv(const float* __restrict__ in, ushort_t* __restrict__ out,
                               int R, int C) {
    __shared__ float tile[32][33];
    int c0 = blockIdx.x * 32, r0 = blockIdx.y * 32;
    int tx = threadIdx.x, ty = threadIdx.y;
#pragma unroll
    for (int k = 0; k < 4; ++k) {
        int a = ty * 4 + k;
        tile[a][tx] = in[(size_t)(r0 + a) * C + c0 + tx];
    }
    __syncthreads();
#pragma unroll
    for (int k = 0; k < 4; ++k) {
        int a = ty * 4 + k;
        out[(size_t)(c0 + a) * R + r0 + tx] = f2b(tile[tx][a]);
    }
}

__global__ void zero_f32(float* __restrict__ p, int n) {
    int i = blockIdx.x * blockDim.x + threadIdx.x;
    if (i < n) p[i] = 0.f;
}

// ---------------- persistent 256x256 8-phase GEMM (16x16x32): C = A @ Bt^T, K=1024 ----------------
// MODE 0: qkv epilogue: bias + elu+1 on q,k.
//   q -> packed ushort4 [bh][n][64]
//   k,v -> BLOCKED [bh][n>>3][64 d][n&7]  (k at +XE, v at +2*XE)
// MODE 1: proj epilogue: bias; fp32 linear [M][Nt]
template<int MODE>
__global__ __launch_bounds__(512, 2) void gemm256(
    const ushort_t* __restrict__ A, const ushort_t* __restrict__ Bt,
    const float* __restrict__ bias,
    ushort_t* __restrict__ out_u16, float* __restrict__ out_f32,
    int Nt, int nbx, int nt)
{
    extern __shared__ ushort_t lds[];   // 65536 elements = 128 KiB
    constexpr int KK = 1024;
    constexpr size_t XEc = (size_t)32768 * 1024;

    const int tid  = threadIdx.x;
    const int wave = tid >> 6;
    const int lane = tid & 63;
    const int wm_i = wave >> 2;
    const int wn_i = wave & 3;
    const int fr   = lane & 15;
    const int fq   = lane >> 4;

    const int bid  = (int)blockIdx.x;
    const int bswz = ((bid & 7) << 5) + (bid >> 3);
    const int ntiles = nt << 8;

    const int trow = tid >> 3;
    const int csw  = ((tid & 7) ^ (trow & 7)) << 3;
    const int tcolB = ((tid >> 8) << 6) + (trow & 31);

    const int dstA = wave * 512;
    const int dstB = 16384 + wave * 512;

    const int sw0 = (fq ^ (fr & 7)) << 3;
    const int sw1 = sw0 ^ 32;
    const int abase = (wm_i * 64 + fr) * 64;
    const int bbase = (wn_i * 32 + fr) * 64;
    int loA0[2][2], loA1[2][2], loB0[2][2], loB1[2][2];
#pragma unroll
    for (int bf = 0; bf < 2; ++bf)
#pragma unroll
        for (int q = 0; q < 2; ++q) {
            loA0[bf][q] = bf * 32768 + q * 8192 + abase + sw0;
            loA1[bf][q] = bf * 32768 + q * 8192 + abase + sw1;
            loB0[bf][q] = bf * 32768 + 16384 + q * 8192 + bbase + sw0;
            loB1[bf][q] = bf * 32768 + 16384 + q * 8192 + bbase + sw1;
        }

    floatx4 acc[8][4];
    const floatx4 z4 = {0.f, 0.f, 0.f, 0.f};
#pragma unroll
    for (int i = 0; i < 8; ++i)
#pragma unroll
        for (int j = 0; j < 4; ++j) acc[i][j] = z4;

    short8 a[4][2], b[2][2];

    auto tilebase = [&](int t, const ushort_t*& sA, const ushort_t*& sB, int& mm, int& nn) {
        const int byy = t / nbx;
        const int bxx = t - byy * nbx;
        mm = byy << 8; nn = bxx << 8;
        sA = A  + (size_t)(mm + trow)  * KK + csw;
        sB = Bt + (size_t)(nn + tcolB) * KK + csw;
    };

    auto stageA = [&](const ushort_t* sp, int buf, int h, int ko) {
        ushort_t* d = lds + buf * 32768 + h * 8192 + dstA;
        GLDS16(sp + h * (64 * KK) + ko, d);
        GLDS16(sp + h * (64 * KK) + 128 * KK + ko, d + 4096);
    };
    auto stageB = [&](const ushort_t* sp, int buf, int h, int ko) {
        ushort_t* d = lds + buf * 32768 + h * 8192 + dstB;
        GLDS16(sp + h * (32 * KK) + ko, d);
        GLDS16(sp + h * (32 * KK) + 128 * KK + ko, d + 4096);
    };
    auto loadA = [&](int buf, int qr) {
        const int o0 = loA0[buf][qr], o1 = loA1[buf][qr];
#pragma unroll
        for (int i = 0; i < 4; ++i) {
            a[i][0] = *(const short8*)(lds + o0 + i * 1024);
            a[i][1] = *(const short8*)(lds + o1 + i * 1024);
        }
    };
    auto loadB = [&](int buf, int qc) {
        const int o0 = loB0[buf][qc], o1 = loB1[buf][qc];
#pragma unroll
        for (int j = 0; j < 2; ++j) {
            b[j][0] = *(const short8*)(lds + o0 + j * 1024);
            b[j][1] = *(const short8*)(lds + o1 + j * 1024);
        }
    };
    auto mma = [&](int qr, int qc) {
#pragma unroll
        for (int i = 0; i < 4; ++i)
#pragma unroll
            for (int j = 0; j < 2; ++j) {
                acc[qr * 4 + i][qc * 2 + j] =
                    __builtin_amdgcn_mfma_f32_16x16x32_bf16(b[j][0], a[i][0], acc[qr * 4 + i][qc * 2 + j], 0, 0, 0);
                acc[qr * 4 + i][qc * 2 + j] =
                    __builtin_amdgcn_mfma_f32_16x16x32_bf16(b[j][1], a[i][1], acc[qr * 4 + i][qc * 2 + j], 0, 0, 0);
            }
    };

    auto epilogue = [&](int m0, int n0) {
        float4 bv[4];
#pragma unroll
        for (int cj = 0; cj < 4; ++cj) {
            const int nb = n0 + wn_i * 64 + (cj >> 1) * 32 + (cj & 1) * 16 + fq * 4;
            bv[cj] = *(const float4*)&bias[nb];
        }
#pragma unroll
        for (int ri = 0; ri < 8; ++ri) {
            const int m = m0 + wm_i * 128 + (ri >> 2) * 64 + (ri & 3) * 16 + fr;
#pragma unroll
            for (int cj = 0; cj < 4; ++cj) {
                const int col = n0 + wn_i * 64 + (cj >> 1) * 32 + (cj & 1) * 16 + fq * 4;
                float v0 = acc[ri][cj][0] + bv[cj].x;
                float v1 = acc[ri][cj][1] + bv[cj].y;
                float v2 = acc[ri][cj][2] + bv[cj].z;
                float v3 = acc[ri][cj][3] + bv[cj].w;
                if (MODE == 0) {
                    const int s  = col >> 10;           // 0=q 1=k 2=v (uniform per tile)
                    const int c  = col & 1023;
                    const int h  = c >> 6;
                    const int d  = c & 63;
                    const int bb = m >> 13;
                    const int n  = m & 8191;
                    const int bh = bb * 16 + h;
                    if (s == 0) {
                        v0 = elu1(v0); v1 = elu1(v1); v2 = elu1(v2); v3 = elu1(v3);
                        ushort4 o;
                        o.x = f2b(v0); o.y = f2b(v1); o.z = f2b(v2); o.w = f2b(v3);
                        *(ushort4*)&out_u16[((size_t)bh * 8192 + n) * 64 + d] = o;
                    } else {
                        if (s == 1) { v0 = elu1(v0); v1 = elu1(v1); v2 = elu1(v2); v3 = elu1(v3); }
                        ushort_t* dst = out_u16 + ((s == 1) ? XEc : 2 * XEc);
                        // blocked layout: [bh][n>>3][64 d][n&7]
                        const size_t base = ((size_t)(bh * 1024 + (n >> 3)) * 64 + d) * 8 + (n & 7);
                        dst[base]      = f2b(v0);
                        dst[base + 8]  = f2b(v1);
                        dst[base + 16] = f2b(v2);
                        dst[base + 24] = f2b(v3);
                    }
                } else {
                    float4 o; o.x = v0; o.y = v1; o.z = v2; o.w = v3;
                    *(float4*)&out_f32[(size_t)m * Nt + col] = o;
                }
            }
        }
    };

#define PRIO1() __builtin_amdgcn_s_setprio(1)
#define BOUT()  __builtin_amdgcn_s_setprio(0); __builtin_amdgcn_s_barrier()
#define VM6()   asm volatile("s_waitcnt vmcnt(6)" ::: "memory")

    const ushort_t *saC, *sbC, *saN, *sbN;
    int m0, n0, m0N, n0N;
    int tC = bswz;
    tilebase(tC, saC, sbC, m0, n0);
    int tN = (tC + 256 < ntiles) ? tC + 256 : tC;
    tilebase(tN, saN, sbN, m0N, n0N);

    stageA(saC, 0, 0, 0);
    stageB(sbC, 0, 1, 0);
    stageA(saC, 0, 1, 0);
    stageB(sbC, 0, 0, 0);
    stageA(saC, 1, 0, 64);
    stageB(sbC, 1, 1, 64);
    stageA(saC, 1, 1, 64);
    VM6();
    __builtin_amdgcn_s_barrier();

    for (int ot = 0; ot < nt; ++ot) {
        int ko = 0;
        for (int pr = 0; pr < 7; ++pr, ko += 128) {
            loadA(0, 0); loadB(0, 0);
            stageB(sbC, 1, 0, ko + 64);
            PRIO1(); mma(0, 0); BOUT();

            loadB(0, 1);
            stageA(saC, 0, 0, ko + 128);
            PRIO1(); mma(0, 1); BOUT();

            loadA(0, 1);
            stageB(sbC, 0, 1, ko + 128);
            PRIO1(); mma(1, 1); BOUT();

            loadB(0, 0);
            stageA(saC, 0, 1, ko + 128);
            PRIO1(); mma(1, 0); __builtin_amdgcn_s_setprio(0); VM6();
            __builtin_amdgcn_s_barrier();

            loadA(1, 0); loadB(1, 0);
            stageB(sbC, 0, 0, ko + 128);
            PRIO1(); mma(0, 0); BOUT();

            loadB(1, 1);
            stageA(saC, 1, 0, ko + 192);
            PRIO1(); mma(0, 1); BOUT();

            loadA(1, 1);
            stageB(sbC, 1, 1, ko + 192);
            PRIO1(); mma(1, 1); BOUT();

            loadB(1, 0);
            stageA(saC, 1, 1, ko + 192);
            PRIO1(); mma(1, 0); __builtin_amdgcn_s_setprio(0); VM6();
            __builtin_amdgcn_s_barrier();
        }

        loadA(0, 0); loadB(0, 0);
        stageB(sbC, 1, 0, 960);
        PRIO1(); mma(0, 0); BOUT();

        loadB(0, 1);
        stageA(saN, 0, 0, 0);
        PRIO1(); mma(0, 1); BOUT();

        loadA(0, 1);
        stageB(sbN, 0, 1, 0);
        PRIO1(); mma(1, 1); BOUT();

        loadB(0, 0);
        stageA(saN, 0, 1, 0);
        PRIO1(); mma(1, 0); __builtin_amdgcn_s_setprio(0); VM6();
        __builtin_amdgcn_s_barrier();

        loadA(1, 0); loadB(1, 0);
        stageB(sbN, 0, 0, 0);
        PRIO1(); mma(0, 0); BOUT();

        loadB(1, 1);
        stageA(saN, 1, 0, 64);
        PRIO1(); mma(0, 1); BOUT();

        loadA(1, 1);
        stageB(sbN, 1, 1, 64);
        PRIO1(); mma(1, 1); BOUT();

        loadB(1, 0);
        stageA(saN, 1, 1, 64);
        PRIO1(); mma(1, 0); __builtin_amdgcn_s_setprio(0); VM6();
        __builtin_amdgcn_s_barrier();

        epilogue(m0, n0);
#pragma unroll
        for (int i = 0; i < 8; ++i)
#pragma unroll
            for (int j = 0; j < 4; ++j) acc[i][j] = z4;

        saC = saN; sbC = sbN; m0 = m0N; n0 = n0N; tC = tN;
        tN = (tC + 256 < ntiles) ? tC + 256 : tC;
        tilebase(tN, saN, sbN, m0N, n0N);
    }

#undef PRIO1
#undef BOUT
#undef VM6
}

// ---------------- kv = k^T v via MFMA from blocked global layout (+ ksum via ones-B) ----------------
// kb/vb: [64 bh][1024 nb][64 d][8 nl] bf16 (k already elu'd).  kv: [bh][d][e] fp32.  ksum: [bh][d].
// grid (8, 64); 256 thr; fragments loaded DIRECTLY from global (b128 = A/B frag); no loop barriers.
__global__ __launch_bounds__(256) void kvg3_kernel(
    const ushort_t* __restrict__ kb, const ushort_t* __restrict__ vb,
    float* __restrict__ kv, float* __restrict__ ksum)
{
    __shared__ float red[4][4096];   // 64 KiB
    __shared__ float ksr[4][64];

    const int bh = blockIdx.y, chunk = blockIdx.x, t = threadIdx.x;
    const int wave = t >> 6, lane = t & 63;
    const int fr = lane & 15, fq = lane >> 4;

    short8 ones;
#pragma unroll
    for (int i = 0; i < 8; ++i) ones[i] = (short)0x3F80;

    floatx4 av[4][4], ak[4];
    const floatx4 z4 = {0.f, 0.f, 0.f, 0.f};
#pragma unroll
    for (int i = 0; i < 4; ++i) {
        ak[i] = z4;
#pragma unroll
        for (int j = 0; j < 4; ++j) av[i][j] = z4;
    }

    // wave handles n-range: chunk*1024 + wave*256 (+ s*32); nb = n>>3
    const size_t base = ((size_t)bh * 1024 + chunk * 128 + wave * 32 + fq) * 512 + fr * 8;
    const ushort_t* kp = kb + base;
    const ushort_t* vp = vb + base;

#pragma unroll 2
    for (int s = 0; s < 8; ++s) {
        short8 ka[4], va[4];
#pragma unroll
        for (int dt = 0; dt < 4; ++dt)
            ka[dt] = *(const short8*)(kp + s * 2048 + dt * 128);
#pragma unroll
        for (int et = 0; et < 4; ++et)
            va[et] = *(const short8*)(vp + s * 2048 + et * 128);
#pragma unroll
        for (int dt = 0; dt < 4; ++dt) {
            ak[dt] = __builtin_amdgcn_mfma_f32_16x16x32_bf16(ka[dt], ones, ak[dt], 0, 0, 0);
#pragma unroll
            for (int et = 0; et < 4; ++et)
                av[dt][et] = __builtin_amdgcn_mfma_f32_16x16x32_bf16(ka[dt], va[et], av[dt][et], 0, 0, 0);
        }
    }

    // wave-private partial dump; C/D: col = fr (e), row = fq*4 + r (d within dt)
#pragma unroll
    for (int dt = 0; dt < 4; ++dt)
#pragma unroll
        for (int et = 0; et < 4; ++et)
#pragma unroll
            for (int r = 0; r < 4; ++r)
                red[wave][(dt * 16 + fq * 4 + r) * 64 + et * 16 + fr] = av[dt][et][r];
    if (fr == 0) {
#pragma unroll
        for (int dt = 0; dt < 4; ++dt)
#pragma unroll
            for (int r = 0; r < 4; ++r)
                ksr[wave][dt * 16 + fq * 4 + r] = ak[dt][r];
    }
    __syncthreads();

#pragma unroll
    for (int j = 0; j < 4; ++j) {
        const int idx = t * 16 + j * 4;
        float4 s0 = *(const float4*)&red[0][idx];
        float4 s1 = *(const float4*)&red[1][idx];
        float4 s2 = *(const float4*)&red[2][idx];
        float4 s3 = *(const float4*)&red[3][idx];
        atomicAdd(&kv[(size_t)bh * 4096 + idx + 0], s0.x + s1.x + s2.x + s3.x);
        atomicAdd(&kv[(size_t)bh * 4096 + idx + 1], s0.y + s1.y + s2.y + s3.y);
        atomicAdd(&kv[(size_t)bh * 4096 + idx + 2], s0.z + s1.z + s2.z + s3.z);
        atomicAdd(&kv[(size_t)bh * 4096 + idx + 3], s0.w + s1.w + s2.w + s3.w);
    }
    if (t < 64) {
        float s = ksr[0][t] + ksr[1][t] + ksr[2][t] + ksr[3][t];
        atomicAdd(&ksum[bh * 64 + t], s);
    }
}

// ---------------- out = (q @ kv) * z via MFMA, repack to [B][N][C] bf16 ----------------
__global__ __launch_bounds__(256) void out_kernel(
    const ushort_t* __restrict__ qbuf, const float* __restrict__ kv,
    const float* __restrict__ ksum, ushort_t* __restrict__ obuf)
{
    __shared__ float kvs[4096];
    __shared__ float ksums[64];

    const int bh = blockIdx.y, chunk = blockIdx.x, t = threadIdx.x;
    const int b = bh >> 4, h = bh & 15;
    const int wave = t >> 6, lane = t & 63;
    const int tok = lane & 15, fq = lane >> 4;

#pragma unroll
    for (int i = 0; i < 4; ++i) {
        int idx = (i * 256 + t) * 4;
        *(float4*)&kvs[idx] = *(const float4*)&kv[(size_t)bh * 4096 + idx];
    }
    if (t < 64) ksums[t] = ksum[bh * 64 + t];
    __syncthreads();

    short8 afr[4][2];
#pragma unroll
    for (int et = 0; et < 4; ++et)
#pragma unroll
        for (int kslice = 0; kslice < 2; ++kslice)
#pragma unroll
            for (int i = 0; i < 8; ++i) {
                const int d = kslice * 32 + fq * 8 + i;
                afr[et][kslice][i] = (short)f2b(kvs[d * 64 + et * 16 + tok]);
            }
    short8 zfr[2];
#pragma unroll
    for (int kslice = 0; kslice < 2; ++kslice)
#pragma unroll
        for (int i = 0; i < 8; ++i)
            zfr[kslice][i] = (short)f2b(ksums[kslice * 32 + fq * 8 + i]);

    const floatx4 z4 = {0.f, 0.f, 0.f, 0.f};
    const int nbase = chunk * 1024 + wave * 256;
    const ushort_t* qrow = qbuf + ((size_t)bh * 8192 + nbase + tok) * 64 + fq * 8;
    ushort_t* orow = obuf + ((size_t)b * 8192 + nbase + tok) * 1024 + h * 64 + fq * 4;

#pragma unroll 2
    for (int g = 0; g < 16; ++g) {
        short8 bf0 = *(const short8*)(qrow + (size_t)g * 16 * 64);
        short8 bf1 = *(const short8*)(qrow + (size_t)g * 16 * 64 + 32);

        floatx4 az = __builtin_amdgcn_mfma_f32_16x16x32_bf16(zfr[0], bf0, z4, 0, 0, 0);
        az = __builtin_amdgcn_mfma_f32_16x16x32_bf16(zfr[1], bf1, az, 0, 0, 0);

        floatx4 ad[4];
#pragma unroll
        for (int et = 0; et < 4; ++et) {
            ad[et] = __builtin_amdgcn_mfma_f32_16x16x32_bf16(afr[et][0], bf0, z4, 0, 0, 0);
            ad[et] = __builtin_amdgcn_mfma_f32_16x16x32_bf16(afr[et][1], bf1, ad[et], 0, 0, 0);
        }

        const float zi = 1.f / (az[0] + 1e-8f);
#pragma unroll
        for (int et = 0; et < 4; ++et) {
            ushort4 o;
            o.x = f2b(ad[et][0] * zi);
            o.y = f2b(ad[et][1] * zi);
            o.z = f2b(ad[et][2] * zi);
            o.w = f2b(ad[et][3] * zi);
            *(ushort4*)&orow[(size_t)g * 16 * 1024 + et * 16] = o;
        }
    }
}

// ---------------- launch ----------------

extern "C" void kernel_launch(void* const* d_in, const int* in_sizes, int n_in,
                              void* d_out, int out_size, void* d_ws, size_t ws_size,
                              hipStream_t stream) {
    const float* x      = (const float*)d_in[0];
    const float* w_qkv  = (const float*)d_in[1];
    const float* b_qkv  = (const float*)d_in[2];
    const float* w_proj = (const float*)d_in[3];
    const float* b_proj = (const float*)d_in[4];
    float* out = (float*)d_out;

    const size_t XE = (size_t)32768 * 1024;

    char* ws = (char*)d_ws;
    ushort_t* xb   = (ushort_t*)ws;  ws += XE * 2;
    ushort_t* wqT  = (ushort_t*)ws;  ws += (size_t)3072 * 1024 * 2;
    ushort_t* wpT  = (ushort_t*)ws;  ws += (size_t)1024 * 1024 * 2;
    ushort_t* qkvb = (ushort_t*)ws;  ws += 3 * XE * 2;   // q [bh][n][64]; k,v blocked [bh][nb][64][8]
    ushort_t* ob   = (ushort_t*)ws;  ws += XE * 2;       // [32768][1024]
    float*    kv   = (float*)ws;     ws += (size_t)64 * 64 * 64 * 4;
    float*    ksum = (float*)ws;     ws += (size_t)64 * 64 * 4;

    (void)hipFuncSetAttribute(reinterpret_cast<const void*>(gemm256<0>),
                              hipFuncAttributeMaxDynamicSharedMemorySize, 131072);
    (void)hipFuncSetAttribute(reinterpret_cast<const void*>(gemm256<1>),
                              hipFuncAttributeMaxDynamicSharedMemorySize, 131072);

    zero_f32<<<dim3((64 * 64 * 64 + 64 * 64 + 255) / 256), dim3(256), 0, stream>>>(kv, 64 * 64 * 64 + 64 * 64);
    conv_bf16<<<dim3(2048), dim3(256), 0, stream>>>(x, xb, (int)(XE / 8));
    transpose_conv<<<dim3(96, 32), dim3(32, 8), 0, stream>>>(w_qkv, wqT, 1024, 3072);
    transpose_conv<<<dim3(32, 32), dim3(32, 8), 0, stream>>>(w_proj, wpT, 1024, 1024);

    // qkv: 1536 tiles, 256 persistent blocks, nt=6
    gemm256<0><<<dim3(256), dim3(512), 131072, stream>>>(xb, wqT, b_qkv, qkvb, nullptr, 3072, 12, 6);

    kvg3_kernel<<<dim3(8, 64), dim3(256), 0, stream>>>(qkvb + XE, qkvb + 2 * XE, kv, ksum);
    out_kernel<<<dim3(8, 64), dim3(256), 0, stream>>>(qkvb, kv, ksum, ob);

    // proj: 512 tiles, 256 persistent blocks, nt=2
    gemm256<1><<<dim3(256), dim3(512), 131072, stream>>>(ob, wpT, b_proj, nullptr, out, 1024, 4, 2);
}

// Round 11
// 480.541 us; speedup vs baseline: 1.0165x; 1.0165x over previous
//
#include <hip/hip_runtime.h>
#include <hip/hip_bf16.h>
#include <stdint.h>

typedef unsigned short ushort_t;
typedef __attribute__((ext_vector_type(8))) short short8;
typedef __attribute__((ext_vector_type(4))) float floatx4;

template<int V> struct IC { static constexpr int value = V; };

__device__ __forceinline__ ushort_t f2b(float f) {
    unsigned u = __float_as_uint(f);
    unsigned r = (u + 0x7FFFu + ((u >> 16) & 1u)) >> 16;
    return (ushort_t)r;
}
__device__ __forceinline__ float b2f(ushort_t h) {
    return __uint_as_float(((unsigned)h) << 16);
}
__device__ __forceinline__ float elu1(float f) {
    return (f > 0.f) ? (f + 1.f) : __expf(f);
}

#define GLDS16(srcp, dstp)                                                          \
    __builtin_amdgcn_global_load_lds(                                               \
        (const __attribute__((address_space(1))) unsigned int*)(srcp),              \
        (__attribute__((address_space(3))) unsigned int*)(dstp), 16, 0, 0)

// ---------------- conversion kernels ----------------

__global__ void conv_bf16(const float* __restrict__ in, ushort_t* __restrict__ out, int n8) {
    for (int i = blockIdx.x * blockDim.x + threadIdx.x; i < n8; i += gridDim.x * blockDim.x) {
        const float4 f0 = *(const float4*)&in[(size_t)i * 8];
        const float4 f1 = *(const float4*)&in[(size_t)i * 8 + 4];
        ushort4 o0, o1;
        o0.x = f2b(f0.x); o0.y = f2b(f0.y); o0.z = f2b(f0.z); o0.w = f2b(f0.w);
        o1.x = f2b(f1.x); o1.y = f2b(f1.y); o1.z = f2b(f1.z); o1.w = f2b(f1.w);
        *(ushort4*)&out[(size_t)i * 8]     = o0;
        *(ushort4*)&out[(size_t)i * 8 + 4] = o1;
    }
}

__global__ void transpose_conv(const float* __restrict__ in, ushort_t* __restrict__ out,
                               int R, int C) {
    __shared__ float tile[32][33];
    int c0 = blockIdx.x * 32, r0 = blockIdx.y * 32;
    int tx = threadIdx.x, ty = threadIdx.y;
#pragma unroll
    for (int k = 0; k < 4; ++k) {
        int a = ty * 4 + k;
        tile[a][tx] = in[(size_t)(r0 + a) * C + c0 + tx];
    }
    __syncthreads();
#pragma unroll
    for (int k = 0; k < 4; ++k) {
        int a = ty * 4 + k;
        out[(size_t)(c0 + a) * R + r0 + tx] = f2b(tile[tx][a]);
    }
}

__global__ void zero_f32(float* __restrict__ p, int n) {
    int i = blockIdx.x * blockDim.x + threadIdx.x;
    if (i < n) p[i] = 0.f;
}

// ---------------- persistent 256x256 8-phase GEMM (16x16x32): C = A @ Bt^T, K=1024 ----------------
// Per-tile orientation (block-uniform): q/proj tiles -> swapped mfma(b,a), packed feature stores;
// k/v tiles -> natural mfma(a,b), packed token stores into blocked [bh][n>>3][64 d][8 nl].
template<int MODE>
__global__ __launch_bounds__(512, 2) void gemm256(
    const ushort_t* __restrict__ A, const ushort_t* __restrict__ Bt,
    const float* __restrict__ bias,
    ushort_t* __restrict__ out_u16, float* __restrict__ out_f32,
    int Nt, int nbx, int nt)
{
    extern __shared__ ushort_t lds[];   // 65536 elements = 128 KiB
    constexpr int KK = 1024;
    constexpr size_t XEc = (size_t)32768 * 1024;

    const int tid  = threadIdx.x;
    const int wave = tid >> 6;
    const int lane = tid & 63;
    const int wm_i = wave >> 2;
    const int wn_i = wave & 3;
    const int fr   = lane & 15;
    const int fq   = lane >> 4;

    const int bid  = (int)blockIdx.x;
    const int bswz = ((bid & 7) << 5) + (bid >> 3);
    const int ntiles = nt << 8;

    const int trow = tid >> 3;
    const int csw  = ((tid & 7) ^ (trow & 7)) << 3;
    const int tcolB = ((tid >> 8) << 6) + (trow & 31);

    const int dstA = wave * 512;
    const int dstB = 16384 + wave * 512;

    const int sw0 = (fq ^ (fr & 7)) << 3;
    const int sw1 = sw0 ^ 32;
    const int abase = (wm_i * 64 + fr) * 64;
    const int bbase = (wn_i * 32 + fr) * 64;
    int loA0[2][2], loA1[2][2], loB0[2][2], loB1[2][2];
#pragma unroll
    for (int bf = 0; bf < 2; ++bf)
#pragma unroll
        for (int q = 0; q < 2; ++q) {
            loA0[bf][q] = bf * 32768 + q * 8192 + abase + sw0;
            loA1[bf][q] = bf * 32768 + q * 8192 + abase + sw1;
            loB0[bf][q] = bf * 32768 + 16384 + q * 8192 + bbase + sw0;
            loB1[bf][q] = bf * 32768 + 16384 + q * 8192 + bbase + sw1;
        }

    floatx4 acc[8][4];
    const floatx4 z4 = {0.f, 0.f, 0.f, 0.f};
#pragma unroll
    for (int i = 0; i < 8; ++i)
#pragma unroll
        for (int j = 0; j < 4; ++j) acc[i][j] = z4;

    short8 a[4][2], b[2][2];

    auto tilebase = [&](int t, const ushort_t*& sA, const ushort_t*& sB, int& mm, int& nn) {
        const int byy = t / nbx;
        const int bxx = t - byy * nbx;
        mm = byy << 8; nn = bxx << 8;
        sA = A  + (size_t)(mm + trow)  * KK + csw;
        sB = Bt + (size_t)(nn + tcolB) * KK + csw;
    };

    auto stageA = [&](const ushort_t* sp, int buf, int h, int ko) {
        ushort_t* d = lds + buf * 32768 + h * 8192 + dstA;
        GLDS16(sp + h * (64 * KK) + ko, d);
        GLDS16(sp + h * (64 * KK) + 128 * KK + ko, d + 4096);
    };
    auto stageB = [&](const ushort_t* sp, int buf, int h, int ko) {
        ushort_t* d = lds + buf * 32768 + h * 8192 + dstB;
        GLDS16(sp + h * (32 * KK) + ko, d);
        GLDS16(sp + h * (32 * KK) + 128 * KK + ko, d + 4096);
    };
    auto loadA = [&](int buf, int qr) {
        const int o0 = loA0[buf][qr], o1 = loA1[buf][qr];
#pragma unroll
        for (int i = 0; i < 4; ++i) {
            a[i][0] = *(const short8*)(lds + o0 + i * 1024);
            a[i][1] = *(const short8*)(lds + o1 + i * 1024);
        }
    };
    auto loadB = [&](int buf, int qc) {
        const int o0 = loB0[buf][qc], o1 = loB1[buf][qc];
#pragma unroll
        for (int j = 0; j < 2; ++j) {
            b[j][0] = *(const short8*)(lds + o0 + j * 1024);
            b[j][1] = *(const short8*)(lds + o1 + j * 1024);
        }
    };
    auto mma = [&](int qr, int qc, auto swc) {
        constexpr int SW = decltype(swc)::value;
#pragma unroll
        for (int i = 0; i < 4; ++i)
#pragma unroll
            for (int j = 0; j < 2; ++j) {
                floatx4& ac = acc[qr * 4 + i][qc * 2 + j];
                if (SW) {
                    ac = __builtin_amdgcn_mfma_f32_16x16x32_bf16(b[j][0], a[i][0], ac, 0, 0, 0);
                    ac = __builtin_amdgcn_mfma_f32_16x16x32_bf16(b[j][1], a[i][1], ac, 0, 0, 0);
                } else {
                    ac = __builtin_amdgcn_mfma_f32_16x16x32_bf16(a[i][0], b[j][0], ac, 0, 0, 0);
                    ac = __builtin_amdgcn_mfma_f32_16x16x32_bf16(a[i][1], b[j][1], ac, 0, 0, 0);
                }
            }
    };

    auto epilogue = [&](int m0, int n0, auto swc) {
        constexpr int SW = decltype(swc)::value;
        if (SW) {
            // swapped: lane = 4 consecutive features; fr = token-within-16
            float4 bv[4];
#pragma unroll
            for (int cj = 0; cj < 4; ++cj) {
                const int nb = n0 + wn_i * 64 + (cj >> 1) * 32 + (cj & 1) * 16 + fq * 4;
                bv[cj] = *(const float4*)&bias[nb];
            }
#pragma unroll
            for (int ri = 0; ri < 8; ++ri) {
                const int m = m0 + wm_i * 128 + (ri >> 2) * 64 + (ri & 3) * 16 + fr;
#pragma unroll
                for (int cj = 0; cj < 4; ++cj) {
                    const int col = n0 + wn_i * 64 + (cj >> 1) * 32 + (cj & 1) * 16 + fq * 4;
                    float v0 = acc[ri][cj][0] + bv[cj].x;
                    float v1 = acc[ri][cj][1] + bv[cj].y;
                    float v2 = acc[ri][cj][2] + bv[cj].z;
                    float v3 = acc[ri][cj][3] + bv[cj].w;
                    if (MODE == 0) {
                        // q tile (col < 1024 guaranteed)
                        const int h  = col >> 6;
                        const int d  = col & 63;
                        const int bb = m >> 13;
                        const int n  = m & 8191;
                        const int bh = bb * 16 + h;
                        v0 = elu1(v0); v1 = elu1(v1); v2 = elu1(v2); v3 = elu1(v3);
                        ushort4 o;
                        o.x = f2b(v0); o.y = f2b(v1); o.z = f2b(v2); o.w = f2b(v3);
                        *(ushort4*)&out_u16[((size_t)bh * 8192 + n) * 64 + d] = o;
                    } else {
                        float4 o; o.x = v0; o.y = v1; o.z = v2; o.w = v3;
                        *(float4*)&out_f32[(size_t)m * Nt + col] = o;
                    }
                }
            }
        } else {
            // natural: lane = 4 consecutive tokens; fr = feature-within-16 (k/v tiles only)
            float bvs[4];
#pragma unroll
            for (int cj = 0; cj < 4; ++cj)
                bvs[cj] = bias[n0 + wn_i * 64 + (cj >> 1) * 32 + (cj & 1) * 16 + fr];
#pragma unroll
            for (int ri = 0; ri < 8; ++ri) {
                const int tok = m0 + wm_i * 128 + (ri >> 2) * 64 + (ri & 3) * 16 + fq * 4;
                const int bb = tok >> 13;
                const int n  = tok & 8191;
#pragma unroll
                for (int cj = 0; cj < 4; ++cj) {
                    const int col = n0 + wn_i * 64 + (cj >> 1) * 32 + (cj & 1) * 16 + fr;
                    const int s = col >> 10;            // 1 or 2
                    const int h = (col & 1023) >> 6;
                    const int d = col & 63;
                    const int bh = bb * 16 + h;
                    float v0 = acc[ri][cj][0] + bvs[cj];
                    float v1 = acc[ri][cj][1] + bvs[cj];
                    float v2 = acc[ri][cj][2] + bvs[cj];
                    float v3 = acc[ri][cj][3] + bvs[cj];
                    if (s == 1) { v0 = elu1(v0); v1 = elu1(v1); v2 = elu1(v2); v3 = elu1(v3); }
                    ushort4 o;
                    o.x = f2b(v0); o.y = f2b(v1); o.z = f2b(v2); o.w = f2b(v3);
                    ushort_t* dst = out_u16 + ((s == 1) ? XEc : 2 * XEc);
                    *(ushort4*)&dst[((size_t)(bh * 1024 + (n >> 3)) * 64 + d) * 8 + (n & 7)] = o;
                }
            }
        }
    };

#define PRIO1() __builtin_amdgcn_s_setprio(1)
#define BOUT()  __builtin_amdgcn_s_setprio(0); __builtin_amdgcn_s_barrier()
#define VM6()   asm volatile("s_waitcnt vmcnt(6)" ::: "memory")

    const ushort_t *saC, *sbC, *saN, *sbN;
    int m0, n0, m0N, n0N;
    int tC = bswz;
    tilebase(tC, saC, sbC, m0, n0);
    int tN = (tC + 256 < ntiles) ? tC + 256 : tC;
    tilebase(tN, saN, sbN, m0N, n0N);

    stageA(saC, 0, 0, 0);
    stageB(sbC, 0, 1, 0);
    stageA(saC, 0, 1, 0);
    stageB(sbC, 0, 0, 0);
    stageA(saC, 1, 0, 64);
    stageB(sbC, 1, 1, 64);
    stageA(saC, 1, 1, 64);
    VM6();
    __builtin_amdgcn_s_barrier();

    auto tile_pass = [&](auto swc) {
        int ko = 0;
        for (int pr = 0; pr < 7; ++pr, ko += 128) {
            loadA(0, 0); loadB(0, 0);
            stageB(sbC, 1, 0, ko + 64);
            PRIO1(); mma(0, 0, swc); BOUT();

            loadB(0, 1);
            stageA(saC, 0, 0, ko + 128);
            PRIO1(); mma(0, 1, swc); BOUT();

            loadA(0, 1);
            stageB(sbC, 0, 1, ko + 128);
            PRIO1(); mma(1, 1, swc); BOUT();

            loadB(0, 0);
            stageA(saC, 0, 1, ko + 128);
            PRIO1(); mma(1, 0, swc); __builtin_amdgcn_s_setprio(0); VM6();
            __builtin_amdgcn_s_barrier();

            loadA(1, 0); loadB(1, 0);
            stageB(sbC, 0, 0, ko + 128);
            PRIO1(); mma(0, 0, swc); BOUT();

            loadB(1, 1);
            stageA(saC, 1, 0, ko + 192);
            PRIO1(); mma(0, 1, swc); BOUT();

            loadA(1, 1);
            stageB(sbC, 1, 1, ko + 192);
            PRIO1(); mma(1, 1, swc); BOUT();

            loadB(1, 0);
            stageA(saC, 1, 1, ko + 192);
            PRIO1(); mma(1, 0, swc); __builtin_amdgcn_s_setprio(0); VM6();
            __builtin_amdgcn_s_barrier();
        }

        loadA(0, 0); loadB(0, 0);
        stageB(sbC, 1, 0, 960);
        PRIO1(); mma(0, 0, swc); BOUT();

        loadB(0, 1);
        stageA(saN, 0, 0, 0);
        PRIO1(); mma(0, 1, swc); BOUT();

        loadA(0, 1);
        stageB(sbN, 0, 1, 0);
        PRIO1(); mma(1, 1, swc); BOUT();

        loadB(0, 0);
        stageA(saN, 0, 1, 0);
        PRIO1(); mma(1, 0, swc); __builtin_amdgcn_s_setprio(0); VM6();
        __builtin_amdgcn_s_barrier();

        loadA(1, 0); loadB(1, 0);
        stageB(sbN, 0, 0, 0);
        PRIO1(); mma(0, 0, swc); BOUT();

        loadB(1, 1);
        stageA(saN, 1, 0, 64);
        PRIO1(); mma(0, 1, swc); BOUT();

        loadA(1, 1);
        stageB(sbN, 1, 1, 64);
        PRIO1(); mma(1, 1, swc); BOUT();

        loadB(1, 0);
        stageA(saN, 1, 1, 64);
        PRIO1(); mma(1, 0, swc); __builtin_amdgcn_s_setprio(0); VM6();
        __builtin_amdgcn_s_barrier();

        epilogue(m0, n0, swc);
#pragma unroll
        for (int i = 0; i < 8; ++i)
#pragma unroll
            for (int j = 0; j < 4; ++j) acc[i][j] = z4;
    };

    for (int ot = 0; ot < nt; ++ot) {
        const bool kvtile = (MODE == 0) && (n0 >= 1024);
        if (kvtile) tile_pass(IC<0>{});
        else        tile_pass(IC<1>{});

        saC = saN; sbC = sbN; m0 = m0N; n0 = n0N; tC = tN;
        tN = (tC + 256 < ntiles) ? tC + 256 : tC;
        tilebase(tN, saN, sbN, m0N, n0N);
    }

#undef PRIO1
#undef BOUT
#undef VM6
}

// ---------------- kv = k^T v via MFMA from blocked global layout (+ ksum via ones-B) ----------------
// kb/vb: [64 bh][1024 nb][64 d][8 nl] bf16 (k already elu'd).  kv: [bh][d][e] fp32.  ksum: [bh][d].
__global__ __launch_bounds__(256) void kvg3_kernel(
    const ushort_t* __restrict__ kb, const ushort_t* __restrict__ vb,
    float* __restrict__ kv, float* __restrict__ ksum)
{
    __shared__ float red[4][4096];   // 64 KiB
    __shared__ float ksr[4][64];

    const int bh = blockIdx.y, chunk = blockIdx.x, t = threadIdx.x;
    const int wave = t >> 6, lane = t & 63;
    const int fr = lane & 15, fq = lane >> 4;

    short8 ones;
#pragma unroll
    for (int i = 0; i < 8; ++i) ones[i] = (short)0x3F80;

    floatx4 av[4][4], ak[4];
    const floatx4 z4 = {0.f, 0.f, 0.f, 0.f};
#pragma unroll
    for (int i = 0; i < 4; ++i) {
        ak[i] = z4;
#pragma unroll
        for (int j = 0; j < 4; ++j) av[i][j] = z4;
    }

    const size_t base = ((size_t)bh * 1024 + chunk * 128 + wave * 32 + fq) * 512 + fr * 8;
    const ushort_t* kp = kb + base;
    const ushort_t* vp = vb + base;

#pragma unroll 2
    for (int s = 0; s < 8; ++s) {
        short8 ka[4], va[4];
#pragma unroll
        for (int dt = 0; dt < 4; ++dt)
            ka[dt] = *(const short8*)(kp + s * 2048 + dt * 128);
#pragma unroll
        for (int et = 0; et < 4; ++et)
            va[et] = *(const short8*)(vp + s * 2048 + et * 128);
#pragma unroll
        for (int dt = 0; dt < 4; ++dt) {
            ak[dt] = __builtin_amdgcn_mfma_f32_16x16x32_bf16(ka[dt], ones, ak[dt], 0, 0, 0);
#pragma unroll
            for (int et = 0; et < 4; ++et)
                av[dt][et] = __builtin_amdgcn_mfma_f32_16x16x32_bf16(ka[dt], va[et], av[dt][et], 0, 0, 0);
        }
    }

#pragma unroll
    for (int dt = 0; dt < 4; ++dt)
#pragma unroll
        for (int et = 0; et < 4; ++et)
#pragma unroll
            for (int r = 0; r < 4; ++r)
                red[wave][(dt * 16 + fq * 4 + r) * 64 + et * 16 + fr] = av[dt][et][r];
    if (fr == 0) {
#pragma unroll
        for (int dt = 0; dt < 4; ++dt)
#pragma unroll
            for (int r = 0; r < 4; ++r)
                ksr[wave][dt * 16 + fq * 4 + r] = ak[dt][r];
    }
    __syncthreads();

#pragma unroll
    for (int j = 0; j < 4; ++j) {
        const int idx = t * 16 + j * 4;
        float4 s0 = *(const float4*)&red[0][idx];
        float4 s1 = *(const float4*)&red[1][idx];
        float4 s2 = *(const float4*)&red[2][idx];
        float4 s3 = *(const float4*)&red[3][idx];
        atomicAdd(&kv[(size_t)bh * 4096 + idx + 0], s0.x + s1.x + s2.x + s3.x);
        atomicAdd(&kv[(size_t)bh * 4096 + idx + 1], s0.y + s1.y + s2.y + s3.y);
        atomicAdd(&kv[(size_t)bh * 4096 + idx + 2], s0.z + s1.z + s2.z + s3.z);
        atomicAdd(&kv[(size_t)bh * 4096 + idx + 3], s0.w + s1.w + s2.w + s3.w);
    }
    if (t < 64) {
        float s = ksr[0][t] + ksr[1][t] + ksr[2][t] + ksr[3][t];
        atomicAdd(&ksum[bh * 64 + t], s);
    }
}

// ---------------- out = (q @ kv) * z via MFMA, repack to [B][N][C] bf16 ----------------
__global__ __launch_bounds__(256) void out_kernel(
    const ushort_t* __restrict__ qbuf, const float* __restrict__ kv,
    const float* __restrict__ ksum, ushort_t* __restrict__ obuf)
{
    __shared__ float kvs[4096];
    __shared__ float ksums[64];

    const int bh = blockIdx.y, chunk = blockIdx.x, t = threadIdx.x;
    const int b = bh >> 4, h = bh & 15;
    const int wave = t >> 6, lane = t & 63;
    const int tok = lane & 15, fq = lane >> 4;

#pragma unroll
    for (int i = 0; i < 4; ++i) {
        int idx = (i * 256 + t) * 4;
        *(float4*)&kvs[idx] = *(const float4*)&kv[(size_t)bh * 4096 + idx];
    }
    if (t < 64) ksums[t] = ksum[bh * 64 + t];
    __syncthreads();

    short8 afr[4][2];
#pragma unroll
    for (int et = 0; et < 4; ++et)
#pragma unroll
        for (int kslice = 0; kslice < 2; ++kslice)
#pragma unroll
            for (int i = 0; i < 8; ++i) {
                const int d = kslice * 32 + fq * 8 + i;
                afr[et][kslice][i] = (short)f2b(kvs[d * 64 + et * 16 + tok]);
            }
    short8 zfr[2];
#pragma unroll
    for (int kslice = 0; kslice < 2; ++kslice)
#pragma unroll
        for (int i = 0; i < 8; ++i)
            zfr[kslice][i] = (short)f2b(ksums[kslice * 32 + fq * 8 + i]);

    const floatx4 z4 = {0.f, 0.f, 0.f, 0.f};
    const int nbase = chunk * 1024 + wave * 256;
    const ushort_t* qrow = qbuf + ((size_t)bh * 8192 + nbase + tok) * 64 + fq * 8;
    ushort_t* orow = obuf + ((size_t)b * 8192 + nbase + tok) * 1024 + h * 64 + fq * 4;

#pragma unroll 2
    for (int g = 0; g < 16; ++g) {
        short8 bf0 = *(const short8*)(qrow + (size_t)g * 16 * 64);
        short8 bf1 = *(const short8*)(qrow + (size_t)g * 16 * 64 + 32);

        floatx4 az = __builtin_amdgcn_mfma_f32_16x16x32_bf16(zfr[0], bf0, z4, 0, 0, 0);
        az = __builtin_amdgcn_mfma_f32_16x16x32_bf16(zfr[1], bf1, az, 0, 0, 0);

        floatx4 ad[4];
#pragma unroll
        for (int et = 0; et < 4; ++et) {
            ad[et] = __builtin_amdgcn_mfma_f32_16x16x32_bf16(afr[et][0], bf0, z4, 0, 0, 0);
            ad[et] = __builtin_amdgcn_mfma_f32_16x16x32_bf16(afr[et][1], bf1, ad[et], 0, 0, 0);
        }

        const float zi = 1.f / (az[0] + 1e-8f);
#pragma unroll
        for (int et = 0; et < 4; ++et) {
            ushort4 o;
            o.x = f2b(ad[et][0] * zi);
            o.y = f2b(ad[et][1] * zi);
            o.z = f2b(ad[et][2] * zi);
            o.w = f2b(ad[et][3] * zi);
            *(ushort4*)&orow[(size_t)g * 16 * 1024 + et * 16] = o;
        }
    }
}

// ---------------- launch ----------------

extern "C" void kernel_launch(void* const* d_in, const int* in_sizes, int n_in,
                              void* d_out, int out_size, void* d_ws, size_t ws_size,
                              hipStream_t stream) {
    const float* x      = (const float*)d_in[0];
    const float* w_qkv  = (const float*)d_in[1];
    const float* b_qkv  = (const float*)d_in[2];
    const float* w_proj = (const float*)d_in[3];
    const float* b_proj = (const float*)d_in[4];
    float* out = (float*)d_out;

    const size_t XE = (size_t)32768 * 1024;

    char* ws = (char*)d_ws;
    ushort_t* xb   = (ushort_t*)ws;  ws += XE * 2;
    ushort_t* wqT  = (ushort_t*)ws;  ws += (size_t)3072 * 1024 * 2;
    ushort_t* wpT  = (ushort_t*)ws;  ws += (size_t)1024 * 1024 * 2;
    ushort_t* qkvb = (ushort_t*)ws;  ws += 3 * XE * 2;   // q [bh][n][64]; k,v blocked [bh][nb][64][8]
    ushort_t* ob   = (ushort_t*)ws;  ws += XE * 2;       // [32768][1024]
    float*    kv   = (float*)ws;     ws += (size_t)64 * 64 * 64 * 4;
    float*    ksum = (float*)ws;     ws += (size_t)64 * 64 * 4;

    (void)hipFuncSetAttribute(reinterpret_cast<const void*>(gemm256<0>),
                              hipFuncAttributeMaxDynamicSharedMemorySize, 131072);
    (void)hipFuncSetAttribute(reinterpret_cast<const void*>(gemm256<1>),
                              hipFuncAttributeMaxDynamicSharedMemorySize, 131072);

    zero_f32<<<dim3((64 * 64 * 64 + 64 * 64 + 255) / 256), dim3(256), 0, stream>>>(kv, 64 * 64 * 64 + 64 * 64);
    conv_bf16<<<dim3(2048), dim3(256), 0, stream>>>(x, xb, (int)(XE / 8));
    transpose_conv<<<dim3(96, 32), dim3(32, 8), 0, stream>>>(w_qkv, wqT, 1024, 3072);
    transpose_conv<<<dim3(32, 32), dim3(32, 8), 0, stream>>>(w_proj, wpT, 1024, 1024);

    // qkv: 1536 tiles, 256 persistent blocks, nt=6
    gemm256<0><<<dim3(256), dim3(512), 131072, stream>>>(xb, wqT, b_qkv, qkvb, nullptr, 3072, 12, 6);

    kvg3_kernel<<<dim3(8, 64), dim3(256), 0, stream>>>(qkvb + XE, qkvb + 2 * XE, kv, ksum);
    out_kernel<<<dim3(8, 64), dim3(256), 0, stream>>>(qkvb, kv, ksum, ob);

    // proj: 512 tiles, 256 persistent blocks, nt=2
    gemm256<1><<<dim3(256), dim3(512), 131072, stream>>>(ob, wpT, b_proj, nullptr, out, 1024, 4, 2);
}